// Round 1
// baseline (1281.196 us; speedup 1.0000x reference)
//
#include <hip/hip_runtime.h>

#define PTOT 131072      // B*H*W
#define IMGP 16384       // H*W
#define BATCH 8
#define CCH 128
#define EPSV 1e-5f

__device__ __forceinline__ float bf2f(unsigned short u){
  union { unsigned int i; float f; } v; v.i = ((unsigned int)u) << 16; return v.f;
}
__device__ __forceinline__ unsigned short f2bf(float f){
  union { float f; unsigned int i; } v; v.f = f;
  unsigned int r = v.i + 0x7FFFu + ((v.i >> 16) & 1u);
  return (unsigned short)(r >> 16);
}
__device__ __forceinline__ float sigmoidf_(float x){ return 1.f/(1.f + __expf(-x)); }

// ---------------- time MLP: all 3 stages, scale/shift per (stage,b,c) ----------------
__global__ __launch_bounds__(256) void k_time_mlp(
    const float* __restrict__ temb,
    const float* __restrict__ w1a, const float* __restrict__ b1a,
    const float* __restrict__ w2a, const float* __restrict__ b2a,
    const float* __restrict__ w1b, const float* __restrict__ b1b,
    const float* __restrict__ w2b, const float* __restrict__ b2b,
    const float* __restrict__ w1c, const float* __restrict__ b1c,
    const float* __restrict__ w2c, const float* __restrict__ b2c,
    float* __restrict__ scsh)
{
  int b = blockIdx.x, s = blockIdx.y, t = threadIdx.x;
  const float* w1 = (s==0)? w1a : ((s==1)? w1b : w1c);
  const float* b1 = (s==0)? b1a : ((s==1)? b1b : b1c);
  const float* w2 = (s==0)? w2a : ((s==1)? w2b : w2c);
  const float* b2 = (s==0)? b2a : ((s==1)? b2b : b2c);
  __shared__ float te[256];
  __shared__ float hb[512];
  te[t] = temb[b*256 + t];
  __syncthreads();
  for (int k = t; k < 512; k += 256){
    float acc = b1[k];
    const float* wr = w1 + (size_t)k*256;
    for (int j = 0; j < 256; j += 4){
      float4 w = *(const float4*)(wr + j);
      acc += w.x*te[j] + w.y*te[j+1] + w.z*te[j+2] + w.w*te[j+3];
    }
    hb[k] = acc * sigmoidf_(acc);
  }
  __syncthreads();
  {
    float acc = b2[t];
    const float* wr = w2 + (size_t)t*512;
    for (int j = 0; j < 512; j += 4){
      float4 w = *(const float4*)(wr + j);
      acc += w.x*hb[j] + w.y*hb[j+1] + w.z*hb[j+2] + w.w*hb[j+3];
    }
    scsh[(size_t)(s*BATCH + b)*256 + t] = acc;
  }
}

// ---------------- group stats: one block per (b,g), 65536 contiguous floats ----------------
__global__ __launch_bounds__(256) void k_stats(const float* __restrict__ x, float* __restrict__ stats)
{
  int bg = blockIdx.x, t = threadIdx.x;
  const float* p = x + (size_t)bg * 65536;
  float s = 0.f, ss = 0.f;
  for (int it = 0; it < 64; ++it){
    float4 v = *(const float4*)(p + it*1024 + t*4);
    s  += v.x + v.y + v.z + v.w;
    ss += v.x*v.x + v.y*v.y + v.z*v.z + v.w*v.w;
  }
  for (int off = 32; off > 0; off >>= 1){
    s  += __shfl_down(s, off, 64);
    ss += __shfl_down(ss, off, 64);
  }
  __shared__ float ps[4], pss[4];
  int w = t >> 6;
  if ((t & 63) == 0){ ps[w] = s; pss[w] = ss; }
  __syncthreads();
  if (t == 0){
    float S  = ps[0]+ps[1]+ps[2]+ps[3];
    float SS = pss[0]+pss[1]+pss[2]+pss[3];
    float m = S * (1.f/65536.f);
    float var = SS * (1.f/65536.f) - m*m;
    stats[bg*2]   = m;
    stats[bg*2+1] = rsqrtf(var + EPSV);
  }
}

// ---------------- generic fp32 GEMM over channels, fused norm-in / bias-silu-res-out ----------------
// out[o][p] = sum_c W[o][c]*in[c][p]; tile: 128 o x 128 px, K-tiles of 32.
__global__ __launch_bounds__(256) void k_gemm(
    const float* __restrict__ xin,           // NORM-mode fp32 input [b][c][16384] (or nullptr)
    const unsigned short* __restrict__ binp, // RAW-mode bf16 input [K][PTOT]     (or nullptr)
    int Ktot,
    const float* __restrict__ Wm,            // [Mtot][Ktot]
    const float* __restrict__ bias,          // [Mtot]
    const float* __restrict__ res,           // nullable fp32 [b][128][16384]
    float* __restrict__ outF,                // nullable fp32 [b][128][16384]
    unsigned short* __restrict__ outB,       // nullable bf16 [Mtot][PTOT]
    int do_silu,
    const float* __restrict__ stats, const float* __restrict__ gnw,
    const float* __restrict__ gnb, const float* __restrict__ scsh,
    const float* __restrict__ modew)
{
  __shared__ float Wt[32][128];
  __shared__ float Ht[32][128];
  __shared__ float An[128], Bn[128];
  int t = threadIdx.x;
  int bimg = blockIdx.x >> 7;
  int p0 = (blockIdx.x & 127) << 7;
  int obase = blockIdx.y << 7;
  bool norm = (xin != nullptr);
  if (norm && t < 128){
    int g = t >> 2;
    float m = stats[(bimg*32+g)*2];
    float r = stats[(bimg*32+g)*2+1];
    float sc = 1.f + scsh[bimg*256 + t];
    float sh = scsh[bimg*256 + 128 + t];
    float gw = gnw[t], gb = gnb[t];
    float a  = r * gw * sc;
    float bb = (gb - m*r*gw)*sc + sh;
    if (modew){ float sg = sigmoidf_(modew[t]); a *= sg; bb *= sg; }
    An[t] = a; Bn[t] = bb;
  }
  float acc[8][8];
  #pragma unroll
  for (int i = 0; i < 8; ++i)
    #pragma unroll
    for (int j = 0; j < 8; ++j) acc[i][j] = 0.f;

  int to = t & 15, tp = t >> 4;
  int wo = t >> 1, wci = (t & 1) << 4;
  int hc = t >> 3, hpi = (t & 7) << 4;

  for (int kt = 0; kt < Ktot; kt += 32){
    __syncthreads();
    { // stage W tile transposed: Wt[c][o]
      const float* src = Wm + (size_t)(obase + wo)*Ktot + kt + wci;
      float4 v0 = *(const float4*)(src+0);
      float4 v1 = *(const float4*)(src+4);
      float4 v2 = *(const float4*)(src+8);
      float4 v3 = *(const float4*)(src+12);
      float tmp[16] = {v0.x,v0.y,v0.z,v0.w, v1.x,v1.y,v1.z,v1.w,
                       v2.x,v2.y,v2.z,v2.w, v3.x,v3.y,v3.z,v3.w};
      #pragma unroll
      for (int j = 0; j < 16; ++j) Wt[wci+j][wo] = tmp[j];
    }
    if (norm){
      const float* src = xin + (size_t)((bimg<<7) + kt + hc)*IMGP + p0 + hpi;
      float a = An[kt+hc], bb = Bn[kt+hc];
      float4 v0 = *(const float4*)(src+0);
      float4 v1 = *(const float4*)(src+4);
      float4 v2 = *(const float4*)(src+8);
      float4 v3 = *(const float4*)(src+12);
      *(float4*)&Ht[hc][hpi+0]  = make_float4(fmaf(v0.x,a,bb), fmaf(v0.y,a,bb), fmaf(v0.z,a,bb), fmaf(v0.w,a,bb));
      *(float4*)&Ht[hc][hpi+4]  = make_float4(fmaf(v1.x,a,bb), fmaf(v1.y,a,bb), fmaf(v1.z,a,bb), fmaf(v1.w,a,bb));
      *(float4*)&Ht[hc][hpi+8]  = make_float4(fmaf(v2.x,a,bb), fmaf(v2.y,a,bb), fmaf(v2.z,a,bb), fmaf(v2.w,a,bb));
      *(float4*)&Ht[hc][hpi+12] = make_float4(fmaf(v3.x,a,bb), fmaf(v3.y,a,bb), fmaf(v3.z,a,bb), fmaf(v3.w,a,bb));
    } else {
      const unsigned short* src = binp + (size_t)(kt+hc)*PTOT + bimg*IMGP + p0 + hpi;
      uint4 u0 = *(const uint4*)(src);
      uint4 u1 = *(const uint4*)(src+8);
      *(float4*)&Ht[hc][hpi+0]  = make_float4(bf2f((unsigned short)u0.x), bf2f((unsigned short)(u0.x>>16)),
                                              bf2f((unsigned short)u0.y), bf2f((unsigned short)(u0.y>>16)));
      *(float4*)&Ht[hc][hpi+4]  = make_float4(bf2f((unsigned short)u0.z), bf2f((unsigned short)(u0.z>>16)),
                                              bf2f((unsigned short)u0.w), bf2f((unsigned short)(u0.w>>16)));
      *(float4*)&Ht[hc][hpi+8]  = make_float4(bf2f((unsigned short)u1.x), bf2f((unsigned short)(u1.x>>16)),
                                              bf2f((unsigned short)u1.y), bf2f((unsigned short)(u1.y>>16)));
      *(float4*)&Ht[hc][hpi+12] = make_float4(bf2f((unsigned short)u1.z), bf2f((unsigned short)(u1.z>>16)),
                                              bf2f((unsigned short)u1.w), bf2f((unsigned short)(u1.w>>16)));
    }
    __syncthreads();
    #pragma unroll 8
    for (int c = 0; c < 32; ++c){
      float wv[8], hv[8];
      *(float4*)&wv[0] = *(const float4*)&Wt[c][to<<3];
      *(float4*)&wv[4] = *(const float4*)&Wt[c][(to<<3)+4];
      *(float4*)&hv[0] = *(const float4*)&Ht[c][tp<<3];
      *(float4*)&hv[4] = *(const float4*)&Ht[c][(tp<<3)+4];
      #pragma unroll
      for (int i = 0; i < 8; ++i)
        #pragma unroll
        for (int j = 0; j < 8; ++j)
          acc[i][j] = fmaf(wv[i], hv[j], acc[i][j]);
    }
  }
  // epilogue
  #pragma unroll
  for (int i = 0; i < 8; ++i){
    int o = (to<<3) + i;
    int og = obase + o;
    float bv = bias[og];
    float v[8];
    #pragma unroll
    for (int j = 0; j < 8; ++j) v[j] = acc[i][j] + bv;
    if (do_silu){
      #pragma unroll
      for (int j = 0; j < 8; ++j) v[j] *= sigmoidf_(v[j]);
    }
    if (res){
      const float* rp = res + (size_t)((bimg<<7) + o)*IMGP + p0 + (tp<<3);
      float4 r0 = *(const float4*)rp;
      float4 r1 = *(const float4*)(rp+4);
      v[0]+=r0.x; v[1]+=r0.y; v[2]+=r0.z; v[3]+=r0.w;
      v[4]+=r1.x; v[5]+=r1.y; v[6]+=r1.z; v[7]+=r1.w;
    }
    if (outF){
      float* op = outF + (size_t)((bimg<<7) + o)*IMGP + p0 + (tp<<3);
      *(float4*)op     = make_float4(v[0],v[1],v[2],v[3]);
      *(float4*)(op+4) = make_float4(v[4],v[5],v[6],v[7]);
    } else {
      unsigned short* op = outB + (size_t)og*PTOT + bimg*IMGP + p0 + (tp<<3);
      ushort4 s0; s0.x=f2bf(v[0]); s0.y=f2bf(v[1]); s0.z=f2bf(v[2]); s0.w=f2bf(v[3]);
      ushort4 s1; s1.x=f2bf(v[4]); s1.y=f2bf(v[5]); s1.z=f2bf(v[6]); s1.w=f2bf(v[7]);
      *(ushort4*)op     = s0;
      *(ushort4*)(op+4) = s1;
    }
  }
}

// ---------------- window attention core: scores + softmax + PV per 4x4 window ----------------
__global__ __launch_bounds__(128) void k_attn(
    const unsigned short* __restrict__ qkv,  // bf16 [384][PTOT], q|k|v each head-major
    const float* __restrict__ relb,          // (49,8)
    unsigned short* __restrict__ ao)         // bf16 [128][PTOT]
{
  __shared__ float qs[8][16][16], ks[8][16][16], vs[8][16][16];
  __shared__ float aot[16][128];
  int t = threadIdx.x;
  int wdw = blockIdx.x;
  int b = wdw >> 10;
  int wi = wdw & 1023;
  int wh = wi >> 5, ww = wi & 31;
  int base = b*IMGP + wh*4*128 + ww*4;
  for (int e = t; e < 6144; e += 128){
    int tq = e & 15;
    int d = (e >> 4) & 15;
    int head = (e >> 8) & 7;
    int sel = e >> 11;
    int o = sel*128 + head*16 + d;
    float val = bf2f(qkv[(size_t)o*PTOT + base + (tq>>2)*128 + (tq&3)]);
    if (sel == 0) qs[head][tq][d] = val;
    else if (sel == 1) ks[head][tq][d] = val;
    else vs[head][tq][d] = val;
  }
  __syncthreads();
  int hh = t >> 4, tq = t & 15;
  float qv[16];
  #pragma unroll
  for (int d = 0; d < 16; ++d) qv[d] = qs[hh][tq][d];
  float sc[16];
  int ty = tq >> 2, tx = tq & 3;
  float mx = -1e30f;
  #pragma unroll
  for (int s = 0; s < 16; ++s){
    float dot = 0.f;
    #pragma unroll
    for (int d = 0; d < 16; ++d) dot = fmaf(qv[d], ks[hh][s][d], dot);
    int sy = s >> 2, sx = s & 3;
    int idx = (ty - sy + 3)*7 + (tx - sx + 3);
    sc[s] = dot*0.25f + relb[idx*8 + hh];
    mx = fmaxf(mx, sc[s]);
  }
  float sum = 0.f;
  #pragma unroll
  for (int s = 0; s < 16; ++s){ sc[s] = __expf(sc[s]-mx); sum += sc[s]; }
  float inv = 1.f/sum;
  float ov[16];
  #pragma unroll
  for (int d = 0; d < 16; ++d) ov[d] = 0.f;
  #pragma unroll
  for (int s = 0; s < 16; ++s)
    #pragma unroll
    for (int d = 0; d < 16; ++d) ov[d] = fmaf(sc[s], vs[hh][s][d], ov[d]);
  #pragma unroll
  for (int d = 0; d < 16; ++d) aot[tq][hh*16+d] = ov[d]*inv;
  __syncthreads();
  int cg = t >> 4;
  for (int it = 0; it < 16; ++it){
    int c = cg*16 + it;
    ao[(size_t)c*PTOT + base + (tq>>2)*128 + (tq&3)] = f2bf(aot[tq][c]);
  }
}

// ---------------- GN + depthwise 3x3 + bias + silu -> bf16 ----------------
__global__ __launch_bounds__(256) void k_dw(
    const float* __restrict__ x,
    const float* __restrict__ stats,
    const float* __restrict__ gnw, const float* __restrict__ gnb,
    const float* __restrict__ dww, const float* __restrict__ dwb,
    unsigned short* __restrict__ outB)
{
  int t = threadIdx.x;
  int blk = blockIdx.x;
  int b = blk >> 13;
  int rem = blk & 8191;
  int c = rem >> 6;
  int rt = rem & 63;
  int h = rt*2 + (t >> 7);
  int w = t & 127;
  int g = c >> 2;
  float m = stats[(b*32+g)*2], r = stats[(b*32+g)*2+1];
  float A  = r*gnw[c];
  float Bc = gnb[c] - m*A;
  const float* xp = x + (size_t)(b*CCH + c)*IMGP;
  float acc = 0.f;
  #pragma unroll
  for (int dy = -1; dy <= 1; ++dy){
    int hh = h + dy;
    if (hh < 0 || hh > 127) continue;
    #pragma unroll
    for (int dx = -1; dx <= 1; ++dx){
      int wp = w + dx;
      if (wp < 0 || wp > 127) continue;
      float xv = xp[hh*128 + wp];
      acc = fmaf(dww[c*9 + (dy+1)*3 + (dx+1)], fmaf(A, xv, Bc), acc);
    }
  }
  acc += dwb[c];
  acc *= sigmoidf_(acc);
  outB[(size_t)c*PTOT + b*IMGP + h*128 + w] = f2bf(acc);
}

extern "C" void kernel_launch(void* const* d_in, const int* in_sizes, int n_in,
                              void* d_out, int out_size, void* d_ws, size_t ws_size,
                              hipStream_t stream)
{
  const float* x0   = (const float*)d_in[0];
  const float* temb = (const float*)d_in[1];
  const float* gn1w = (const float*)d_in[2];
  const float* gn1b = (const float*)d_in[3];
  const float* t1w1 = (const float*)d_in[4];
  const float* t1b1 = (const float*)d_in[5];
  const float* t1w2 = (const float*)d_in[6];
  const float* t1b2 = (const float*)d_in[7];
  const float* specw= (const float*)d_in[8];
  const float* specb= (const float*)d_in[9];
  const float* modew= (const float*)d_in[10];
  const float* gn2w = (const float*)d_in[11];
  const float* gn2b = (const float*)d_in[12];
  const float* t2w1 = (const float*)d_in[13];
  const float* t2b1 = (const float*)d_in[14];
  const float* t2w2 = (const float*)d_in[15];
  const float* t2b2 = (const float*)d_in[16];
  const float* qkvw = (const float*)d_in[17];
  const float* qkvb = (const float*)d_in[18];
  const float* projw= (const float*)d_in[19];
  const float* projb= (const float*)d_in[20];
  const float* relb = (const float*)d_in[21];
  const float* gn3w = (const float*)d_in[22];
  const float* gn3b = (const float*)d_in[23];
  const float* t3w1 = (const float*)d_in[24];
  const float* t3b1 = (const float*)d_in[25];
  const float* t3w2 = (const float*)d_in[26];
  const float* t3b2 = (const float*)d_in[27];
  const float* mlpw1= (const float*)d_in[28];
  const float* mlpb1= (const float*)d_in[29];
  const float* mlpw2= (const float*)d_in[30];
  const float* mlpb2= (const float*)d_in[31];
  const float* sbgnw= (const float*)d_in[32];
  const float* sbgnb= (const float*)d_in[33];
  const float* dww  = (const float*)d_in[34];
  const float* dwb  = (const float*)d_in[35];
  const float* pww  = (const float*)d_in[36];
  const float* pwb  = (const float*)d_in[37];
  float* out = (float*)d_out;

  char* ws = (char*)d_ws;
  float* SC    = (float*)ws;                        // 3*8*256 floats
  float* STATS = (float*)(ws + (64u<<10));          // 512 floats
  float* X1    = (float*)(ws + (1u<<20));           // 64 MiB fp32
  char* BIG    = ws + (1u<<20) + ((size_t)64<<20);  // 128 MiB region
  unsigned short* QKV = (unsigned short*)BIG;                         // 96 MiB
  unsigned short* AO  = (unsigned short*)(BIG + ((size_t)96<<20));    // 32 MiB
  unsigned short* H1  = (unsigned short*)BIG;                         // 128 MiB (reuse)
  unsigned short* DWO = (unsigned short*)BIG;                         // 32 MiB (reuse)

  // 1. time-MLP scale/shift for all 3 AdaGN stages
  k_time_mlp<<<dim3(8,3), 256, 0, stream>>>(temb,
      t1w1,t1b1,t1w2,t1b2, t2w1,t2b1,t2w2,t2b2, t3w1,t3b1,t3w2,t3b2, SC);

  // --- stage 1: AdaGN -> mode-weight -> spectral conv1x1 -> silu -> +x ---
  k_stats<<<256, 256, 0, stream>>>(x0, STATS);
  k_gemm<<<dim3(1024,1), 256, 0, stream>>>(x0, nullptr, 128, specw, specb,
      x0, X1, nullptr, 1, STATS, gn1w, gn1b, SC + 0, modew);

  // --- stage 2: AdaGN -> window attention -> +x ---
  k_stats<<<256, 256, 0, stream>>>(X1, STATS);
  k_gemm<<<dim3(1024,3), 256, 0, stream>>>(X1, nullptr, 128, qkvw, qkvb,
      nullptr, nullptr, QKV, 0, STATS, gn2w, gn2b, SC + 2048, nullptr);
  k_attn<<<8192, 128, 0, stream>>>(QKV, relb, AO);
  k_gemm<<<dim3(1024,1), 256, 0, stream>>>(nullptr, AO, 128, projw, projb,
      X1, out, nullptr, 0, nullptr, nullptr, nullptr, nullptr, nullptr);

  // --- stage 3: AdaGN -> MLP (128->512 silu ->128) -> +x ---
  k_stats<<<256, 256, 0, stream>>>(out, STATS);
  k_gemm<<<dim3(1024,4), 256, 0, stream>>>(out, nullptr, 128, mlpw1, mlpb1,
      nullptr, nullptr, H1, 1, STATS, gn3w, gn3b, SC + 4096, nullptr);
  k_gemm<<<dim3(1024,1), 256, 0, stream>>>(nullptr, H1, 512, mlpw2, mlpb2,
      out, out, nullptr, 0, nullptr, nullptr, nullptr, nullptr, nullptr);

  // --- stage 4: GN -> dw3x3 -> silu -> pw conv1x1 -> +x ---
  k_stats<<<256, 256, 0, stream>>>(out, STATS);
  k_dw<<<65536, 256, 0, stream>>>(out, STATS, sbgnw, sbgnb, dww, dwb, DWO);
  k_gemm<<<dim3(1024,1), 256, 0, stream>>>(nullptr, DWO, 128, pww, pwb,
      out, out, nullptr, 0, nullptr, nullptr, nullptr, nullptr, nullptr);
}

// Round 2
// 789.275 us; speedup vs baseline: 1.6233x; 1.6233x over previous
//
#include <hip/hip_runtime.h>

#define PTOT 131072      // B*H*W
#define IMGP 16384       // H*W
#define BATCH 8
#define CCH 128
#define EPSV 1e-5f

typedef short bf16x8 __attribute__((ext_vector_type(8)));
typedef float f32x4 __attribute__((ext_vector_type(4)));

__device__ __forceinline__ float bf2f(unsigned short u){
  union { unsigned int i; float f; } v; v.i = ((unsigned int)u) << 16; return v.f;
}
__device__ __forceinline__ unsigned short f2bf(float f){
  union { float f; unsigned int i; } v; v.f = f;
  unsigned int r = v.i + 0x7FFFu + ((v.i >> 16) & 1u);
  return (unsigned short)(r >> 16);
}
__device__ __forceinline__ unsigned int pk2(float a, float b){
  return (unsigned int)f2bf(a) | ((unsigned int)f2bf(b) << 16);
}
__device__ __forceinline__ float sigmoidf_(float x){ return 1.f/(1.f + __expf(-x)); }

// ---------------- time MLP: all 3 stages ----------------
__global__ __launch_bounds__(256) void k_time_mlp(
    const float* __restrict__ temb,
    const float* __restrict__ w1a, const float* __restrict__ b1a,
    const float* __restrict__ w2a, const float* __restrict__ b2a,
    const float* __restrict__ w1b, const float* __restrict__ b1b,
    const float* __restrict__ w2b, const float* __restrict__ b2b,
    const float* __restrict__ w1c, const float* __restrict__ b1c,
    const float* __restrict__ w2c, const float* __restrict__ b2c,
    float* __restrict__ scsh)
{
  int b = blockIdx.x, s = blockIdx.y, t = threadIdx.x;
  const float* w1 = (s==0)? w1a : ((s==1)? w1b : w1c);
  const float* b1 = (s==0)? b1a : ((s==1)? b1b : b1c);
  const float* w2 = (s==0)? w2a : ((s==1)? w2b : w2c);
  const float* b2 = (s==0)? b2a : ((s==1)? b2b : b2c);
  __shared__ float te[256];
  __shared__ float hb[512];
  te[t] = temb[b*256 + t];
  __syncthreads();
  for (int k = t; k < 512; k += 256){
    float acc = b1[k];
    const float* wr = w1 + (size_t)k*256;
    for (int j = 0; j < 256; j += 4){
      float4 w = *(const float4*)(wr + j);
      acc += w.x*te[j] + w.y*te[j+1] + w.z*te[j+2] + w.w*te[j+3];
    }
    hb[k] = acc * sigmoidf_(acc);
  }
  __syncthreads();
  {
    float acc = b2[t];
    const float* wr = w2 + (size_t)t*512;
    for (int j = 0; j < 512; j += 4){
      float4 w = *(const float4*)(wr + j);
      acc += w.x*hb[j] + w.y*hb[j+1] + w.z*hb[j+2] + w.w*hb[j+3];
    }
    scsh[(size_t)(s*BATCH + b)*256 + t] = acc;
  }
}

// ---------------- stage-1 stats from x0 [c][p]: raw (S,SS) per (b,g) ----------------
__global__ __launch_bounds__(256) void k_stats(const float* __restrict__ x, float* __restrict__ SG)
{
  int bg = blockIdx.x, t = threadIdx.x;
  const float* p = x + (size_t)bg * 65536;
  float s = 0.f, ss = 0.f;
  for (int it = 0; it < 64; ++it){
    float4 v = *(const float4*)(p + it*1024 + t*4);
    s  += v.x + v.y + v.z + v.w;
    ss += v.x*v.x + v.y*v.y + v.z*v.z + v.w*v.w;
  }
  for (int off = 32; off > 0; off >>= 1){
    s  += __shfl_down(s, off, 64);
    ss += __shfl_down(ss, off, 64);
  }
  __shared__ float ps[4], pss[4];
  int w = t >> 6;
  if ((t & 63) == 0){ ps[w] = s; pss[w] = ss; }
  __syncthreads();
  if (t == 0){
    SG[bg*2]   = ps[0]+ps[1]+ps[2]+ps[3];
    SG[bg*2+1] = pss[0]+pss[1]+pss[2]+pss[3];
  }
}

// ---------------- stats from XR [p][128]: atomic raw sums (memset SG first) ----------------
__global__ __launch_bounds__(256) void k_statsT(const float* __restrict__ XR, float* __restrict__ SG)
{
  int bx = blockIdx.x;
  int b = bx >> 5, chunk = bx & 31;
  int t = threadIdx.x;
  int g = t & 31, pxi = t >> 5;
  const float* base = XR + ((size_t)(b*IMGP + chunk*512 + pxi))*128 + g*4;
  float s = 0.f, ss = 0.f;
  for (int i = 0; i < 64; ++i){
    float4 v = *(const float4*)(base + (size_t)i*8*128);
    s  += v.x + v.y + v.z + v.w;
    ss += v.x*v.x + v.y*v.y + v.z*v.z + v.w*v.w;
  }
  __shared__ float rs[8][33], rss[8][33];
  rs[pxi][g] = s; rss[pxi][g] = ss;
  __syncthreads();
  if (t < 32){
    float S = 0.f, SS = 0.f;
    #pragma unroll
    for (int i = 0; i < 8; ++i){ S += rs[i][t]; SS += rss[i][t]; }
    atomicAdd(&SG[(b*32+t)*2],   S);
    atomicAdd(&SG[(b*32+t)*2+1], SS);
  }
}

// ---------------- bf16 MFMA GEMM over channels, layout [p][c] ----------------
// C[o][p] = sum_c W[o][c]*X[p][c]; block tile 128o x 128px, BK=64, 4 waves 2x2.
__global__ __launch_bounds__(256) void k_gemm_mfma(
    const float* __restrict__ xinT,          // norm path: fp32 XR [p][128] (or null)
    const float* __restrict__ xinC,          // normT path: fp32 x0 [c][p]  (or null)
    const unsigned short* __restrict__ binp, // raw path: bf16 [p][Ktot]    (or null)
    int Ktot,
    const float* __restrict__ Wm,            // [Mtot][Ktot] fp32
    const float* __restrict__ bias,          // [Mtot]
    const float* __restrict__ resT,          // fp32 [p][128] or null
    const float* __restrict__ resC,          // fp32 [c][p] or null
    float* __restrict__ outT,                // fp32 [p][128] or null
    unsigned short* __restrict__ outB,       // bf16 [p][Mtot] or null
    float* __restrict__ outC,                // fp32 [c][p] or null
    int Mtot, int do_silu,
    const float* __restrict__ SG, const float* __restrict__ gnw,
    const float* __restrict__ gnb, const float* __restrict__ scsh,
    const float* __restrict__ modew)
{
  __shared__ __align__(16) unsigned short As[128*72];
  __shared__ __align__(16) unsigned short Bs[128*72];
  __shared__ float An[128], Bn[128];
  int t = threadIdx.x;
  int p0 = blockIdx.x << 7;
  int bimg = p0 >> 14;
  int hw0 = p0 & 16383;
  int obase = blockIdx.y << 7;

  bool normP = (xinT != nullptr);
  bool normT = (xinC != nullptr);
  if ((normP || normT) && t < 128){
    int g = t >> 2;
    float S  = SG[(bimg*32+g)*2];
    float SS = SG[(bimg*32+g)*2+1];
    float m = S * (1.f/65536.f);
    float r = rsqrtf(SS*(1.f/65536.f) - m*m + EPSV);
    float sc = 1.f + scsh[bimg*256 + t];
    float sh = scsh[bimg*256 + 128 + t];
    float gw = gnw[t];
    float a  = r * gw * sc;
    float bb = (gnb[t] - m*r*gw)*sc + sh;
    if (modew){ float sg = sigmoidf_(modew[t]); a *= sg; bb *= sg; }
    An[t] = a; Bn[t] = bb;
  }

  f32x4 acc[4][4];
  #pragma unroll
  for (int i = 0; i < 4; ++i)
    #pragma unroll
    for (int j = 0; j < 4; ++j){ f32x4 z = {0.f,0.f,0.f,0.f}; acc[i][j] = z; }

  int lane = t & 63, wid = t >> 6;
  int wo = (wid & 1) << 6, wp = (wid >> 1) << 6;
  int quad = lane >> 4, l15 = lane & 15;

  int aso = t >> 1, ash = (t & 1) << 5;

  int nchunks = Ktot >> 6;
  for (int kc = 0; kc < nchunks; ++kc){
    int kt = kc << 6;
    __syncthreads();
    { // A: weights fp32 -> bf16 LDS [o][72c-row]
      const float* src = Wm + (size_t)(obase + aso)*Ktot + kt + ash;
      unsigned short* dst = As + aso*72 + ash;
      #pragma unroll
      for (int j = 0; j < 4; ++j){
        float4 v0 = *(const float4*)(src + j*8);
        float4 v1 = *(const float4*)(src + j*8 + 4);
        uint4 w;
        w.x = pk2(v0.x, v0.y); w.y = pk2(v0.z, v0.w);
        w.z = pk2(v1.x, v1.y); w.w = pk2(v1.z, v1.w);
        *(uint4*)(dst + j*8) = w;
      }
    }
    if (normP){
      int pcs = t & 15, ppx = t >> 4;
      float4 a4 = *(const float4*)&An[kt + pcs*4];
      float4 b4 = *(const float4*)&Bn[kt + pcs*4];
      #pragma unroll
      for (int pass = 0; pass < 8; ++pass){
        int px = ppx + (pass << 4);
        float4 v = *(const float4*)(xinT + (size_t)(p0+px)*128 + kt + pcs*4);
        float x0 = fmaf(v.x, a4.x, b4.x);
        float x1 = fmaf(v.y, a4.y, b4.y);
        float x2 = fmaf(v.z, a4.z, b4.z);
        float x3 = fmaf(v.w, a4.w, b4.w);
        uint2 w; w.x = pk2(x0, x1); w.y = pk2(x2, x3);
        *(uint2*)(Bs + px*72 + pcs*4) = w;
      }
    } else if (normT){
      int ncs = t >> 5, npx = t & 31;
      int c0 = kt + ncs*8;
      const float* src = xinC + (size_t)(bimg*128 + c0)*IMGP + hw0 + npx;
      #pragma unroll
      for (int i = 0; i < 4; ++i){
        float vv[8];
        #pragma unroll
        for (int r = 0; r < 8; ++r)
          vv[r] = fmaf(src[(size_t)r*IMGP + (i<<5)], An[c0+r], Bn[c0+r]);
        uint4 w;
        w.x = pk2(vv[0], vv[1]); w.y = pk2(vv[2], vv[3]);
        w.z = pk2(vv[4], vv[5]); w.w = pk2(vv[6], vv[7]);
        *(uint4*)(Bs + (npx + (i<<5))*72 + ncs*8) = w;
      }
    } else {
      int rcs = t & 7, rpx = t >> 3;
      #pragma unroll
      for (int i = 0; i < 4; ++i){
        int px = rpx + (i << 5);
        uint4 v = *(const uint4*)(binp + (size_t)(p0+px)*Ktot + kt + rcs*8);
        *(uint4*)(Bs + px*72 + rcs*8) = v;
      }
    }
    __syncthreads();
    #pragma unroll
    for (int s = 0; s < 2; ++s){
      bf16x8 af[4], bfv[4];
      #pragma unroll
      for (int i = 0; i < 4; ++i){
        af[i]  = *(const bf16x8*)(As + (wo + i*16 + l15)*72 + s*32 + quad*8);
        bfv[i] = *(const bf16x8*)(Bs + (wp + i*16 + l15)*72 + s*32 + quad*8);
      }
      #pragma unroll
      for (int i = 0; i < 4; ++i)
        #pragma unroll
        for (int j = 0; j < 4; ++j)
          acc[i][j] = __builtin_amdgcn_mfma_f32_16x16x32_bf16(af[i], bfv[j], acc[i][j], 0, 0, 0);
    }
  }

  // epilogue
  #pragma unroll
  for (int i = 0; i < 4; ++i){
    int o4 = wo + i*16 + (quad << 2);
    float4 bv = *(const float4*)&bias[obase + o4];
    #pragma unroll
    for (int j = 0; j < 4; ++j){
      int px = p0 + wp + j*16 + l15;
      int hw = px & 16383;
      float v0 = acc[i][j][0] + bv.x;
      float v1 = acc[i][j][1] + bv.y;
      float v2 = acc[i][j][2] + bv.z;
      float v3 = acc[i][j][3] + bv.w;
      if (do_silu){
        v0 *= sigmoidf_(v0); v1 *= sigmoidf_(v1);
        v2 *= sigmoidf_(v2); v3 *= sigmoidf_(v3);
      }
      if (resT){
        float4 rv = *(const float4*)(resT + (size_t)px*128 + o4);
        v0 += rv.x; v1 += rv.y; v2 += rv.z; v3 += rv.w;
      }
      if (resC){
        const float* rp = resC + (size_t)(bimg*128 + o4)*IMGP + hw;
        v0 += rp[0]; v1 += rp[IMGP]; v2 += rp[2*IMGP]; v3 += rp[3*IMGP];
      }
      if (outT){
        *(float4*)(outT + (size_t)px*128 + o4) = make_float4(v0, v1, v2, v3);
      }
      if (outB){
        uint2 w; w.x = pk2(v0, v1); w.y = pk2(v2, v3);
        *(uint2*)(outB + (size_t)px*Mtot + obase + o4) = w;
      }
      if (outC){
        float* op = outC + (size_t)(bimg*128 + o4)*IMGP + hw;
        op[0] = v0; op[IMGP] = v1; op[2*IMGP] = v2; op[3*IMGP] = v3;
      }
    }
  }
}

// ---------------- window attention: QKV bf16 [p][384] -> AO bf16 [p][128] ----------------
__global__ __launch_bounds__(128) void k_attn(
    const unsigned short* __restrict__ qkv,
    const float* __restrict__ relb,          // (49,8)
    unsigned short* __restrict__ ao)
{
  __shared__ float qs[8][16][16], ks[8][16][16], vs[8][16][16];
  __shared__ float aot[16][128];
  int t = threadIdx.x;
  int blk = blockIdx.x;
  int b = blk >> 10;
  int wi = blk & 1023;
  int wh = wi >> 5, ww = wi & 31;
  int base_p = b*IMGP + wh*512 + ww*4;
  for (int e = t; e < 6144; e += 128){
    int d = e & 15;
    int tq = (e >> 4) & 15;
    int head = (e >> 8) & 7;
    int sel = e >> 11;
    int p = base_p + (tq >> 2)*128 + (tq & 3);
    float val = bf2f(qkv[(size_t)p*384 + sel*128 + head*16 + d]);
    if (sel == 0) qs[head][tq][d] = val;
    else if (sel == 1) ks[head][tq][d] = val;
    else vs[head][tq][d] = val;
  }
  __syncthreads();
  int hh = t >> 4, tq = t & 15;
  float qv[16];
  #pragma unroll
  for (int d = 0; d < 16; ++d) qv[d] = qs[hh][tq][d];
  float sc[16];
  int ty = tq >> 2, tx = tq & 3;
  float mx = -1e30f;
  #pragma unroll
  for (int s = 0; s < 16; ++s){
    float dot = 0.f;
    #pragma unroll
    for (int d = 0; d < 16; ++d) dot = fmaf(qv[d], ks[hh][s][d], dot);
    int sy = s >> 2, sx = s & 3;
    int idx = (ty - sy + 3)*7 + (tx - sx + 3);
    sc[s] = dot*0.25f + relb[idx*8 + hh];
    mx = fmaxf(mx, sc[s]);
  }
  float sum = 0.f;
  #pragma unroll
  for (int s = 0; s < 16; ++s){ sc[s] = __expf(sc[s]-mx); sum += sc[s]; }
  float inv = 1.f/sum;
  float ov[16];
  #pragma unroll
  for (int d = 0; d < 16; ++d) ov[d] = 0.f;
  #pragma unroll
  for (int s = 0; s < 16; ++s)
    #pragma unroll
    for (int d = 0; d < 16; ++d) ov[d] = fmaf(sc[s], vs[hh][s][d], ov[d]);
  #pragma unroll
  for (int d = 0; d < 16; ++d) aot[tq][hh*16+d] = ov[d]*inv;
  __syncthreads();
  int c8 = t & 15;
  #pragma unroll
  for (int iter = 0; iter < 2; ++iter){
    int tq2 = (t >> 4) + iter*8;
    int p = base_p + (tq2 >> 2)*128 + (tq2 & 3);
    const float* ap = &aot[tq2][c8*8];
    uint4 w;
    w.x = pk2(ap[0], ap[1]); w.y = pk2(ap[2], ap[3]);
    w.z = pk2(ap[4], ap[5]); w.w = pk2(ap[6], ap[7]);
    *(uint4*)(ao + (size_t)p*128 + c8*8) = w;
  }
}

// ---------------- GN + depthwise 3x3 + bias + silu, XR [p][128] -> DWO bf16 [p][128] ----------------
__global__ __launch_bounds__(256) void k_dw(
    const float* __restrict__ XR,
    const float* __restrict__ SG,
    const float* __restrict__ gnw, const float* __restrict__ gnb,
    const float* __restrict__ dww, const float* __restrict__ dwb,
    unsigned short* __restrict__ DWO)
{
  __shared__ float wt[9][128];
  __shared__ float Af[128], Bf[128];
  int t = threadIdx.x;
  int p0 = blockIdx.x * 8;
  int b = p0 >> 14;
  if (t < 128){
    int g = t >> 2;
    float S  = SG[(b*32+g)*2];
    float SS = SG[(b*32+g)*2+1];
    float m = S * (1.f/65536.f);
    float r = rsqrtf(SS*(1.f/65536.f) - m*m + EPSV);
    float A = r * gnw[t];
    Af[t] = A;
    Bf[t] = gnb[t] - m*A;
  }
  for (int j = t; j < 1152; j += 256) wt[j % 9][j / 9] = dww[j];
  __syncthreads();
  int cq = t & 31, pxi = t >> 5;
  int px = p0 + pxi;
  int hw = px & 16383;
  int h = hw >> 7, w = hw & 127;
  int c4 = cq << 2;
  float4 A4 = *(const float4*)&Af[c4];
  float4 B4 = *(const float4*)&Bf[c4];
  float4 acc = *(const float4*)&dwb[c4];
  #pragma unroll
  for (int dy = -1; dy <= 1; ++dy){
    int hh = h + dy;
    if (hh < 0 || hh > 127) continue;
    #pragma unroll
    for (int dx = -1; dx <= 1; ++dx){
      int wp = w + dx;
      if (wp < 0 || wp > 127) continue;
      const float* xp = XR + (size_t)(px + dy*128 + dx)*128 + c4;
      float4 xv = *(const float4*)xp;
      float4 wv = *(const float4*)&wt[(dy+1)*3 + (dx+1)][c4];
      acc.x = fmaf(wv.x, fmaf(A4.x, xv.x, B4.x), acc.x);
      acc.y = fmaf(wv.y, fmaf(A4.y, xv.y, B4.y), acc.y);
      acc.z = fmaf(wv.z, fmaf(A4.z, xv.z, B4.z), acc.z);
      acc.w = fmaf(wv.w, fmaf(A4.w, xv.w, B4.w), acc.w);
    }
  }
  acc.x *= sigmoidf_(acc.x); acc.y *= sigmoidf_(acc.y);
  acc.z *= sigmoidf_(acc.z); acc.w *= sigmoidf_(acc.w);
  uint2 o; o.x = pk2(acc.x, acc.y); o.y = pk2(acc.z, acc.w);
  *(uint2*)(DWO + (size_t)px*128 + c4) = o;
}

extern "C" void kernel_launch(void* const* d_in, const int* in_sizes, int n_in,
                              void* d_out, int out_size, void* d_ws, size_t ws_size,
                              hipStream_t stream)
{
  const float* x0   = (const float*)d_in[0];
  const float* temb = (const float*)d_in[1];
  const float* gn1w = (const float*)d_in[2];
  const float* gn1b = (const float*)d_in[3];
  const float* t1w1 = (const float*)d_in[4];
  const float* t1b1 = (const float*)d_in[5];
  const float* t1w2 = (const float*)d_in[6];
  const float* t1b2 = (const float*)d_in[7];
  const float* specw= (const float*)d_in[8];
  const float* specb= (const float*)d_in[9];
  const float* modew= (const float*)d_in[10];
  const float* gn2w = (const float*)d_in[11];
  const float* gn2b = (const float*)d_in[12];
  const float* t2w1 = (const float*)d_in[13];
  const float* t2b1 = (const float*)d_in[14];
  const float* t2w2 = (const float*)d_in[15];
  const float* t2b2 = (const float*)d_in[16];
  const float* qkvw = (const float*)d_in[17];
  const float* qkvb = (const float*)d_in[18];
  const float* projw= (const float*)d_in[19];
  const float* projb= (const float*)d_in[20];
  const float* relb = (const float*)d_in[21];
  const float* gn3w = (const float*)d_in[22];
  const float* gn3b = (const float*)d_in[23];
  const float* t3w1 = (const float*)d_in[24];
  const float* t3b1 = (const float*)d_in[25];
  const float* t3w2 = (const float*)d_in[26];
  const float* t3b2 = (const float*)d_in[27];
  const float* mlpw1= (const float*)d_in[28];
  const float* mlpb1= (const float*)d_in[29];
  const float* mlpw2= (const float*)d_in[30];
  const float* mlpb2= (const float*)d_in[31];
  const float* sbgnw= (const float*)d_in[32];
  const float* sbgnb= (const float*)d_in[33];
  const float* dww  = (const float*)d_in[34];
  const float* dwb  = (const float*)d_in[35];
  const float* pww  = (const float*)d_in[36];
  const float* pwb  = (const float*)d_in[37];
  float* out = (float*)d_out;

  char* ws = (char*)d_ws;
  float* SC = (float*)ws;                                   // 24 KB
  float* SG = (float*)(ws + 32768);                         // 4 stages x 512 floats
  float* SG1 = SG, *SG2 = SG + 512, *SG3 = SG + 1024, *SG4 = SG + 1536;
  float* XR = (float*)(ws + (1u<<20));                      // 64 MiB fp32 [p][128]
  char* BIG = ws + (1u<<20) + ((size_t)64<<20);             // 128 MiB
  unsigned short* QKV = (unsigned short*)BIG;                       // 96 MiB [p][384]
  unsigned short* AO  = (unsigned short*)(BIG + ((size_t)96<<20));  // 32 MiB [p][128]
  unsigned short* H1  = (unsigned short*)BIG;                       // 128 MiB [p][512]
  unsigned short* DWO = (unsigned short*)BIG;                       // 32 MiB [p][128]

  hipMemsetAsync(SG, 0, 4*512*sizeof(float), stream);

  k_time_mlp<<<dim3(8,3), 256, 0, stream>>>(temb,
      t1w1,t1b1,t1w2,t1b2, t2w1,t2b1,t2w2,t2b2, t3w1,t3b1,t3w2,t3b2, SC);

  // stage 1: AdaGN*sig(modew) -> spec 1x1 -> silu -> + x0  => XR (=x1, [p][c])
  k_stats<<<256, 256, 0, stream>>>(x0, SG1);
  k_gemm_mfma<<<dim3(1024,1), 256, 0, stream>>>(
      nullptr, x0, nullptr, 128, specw, specb,
      nullptr, x0, XR, nullptr, nullptr, 128, 1,
      SG1, gn1w, gn1b, SC + 0, modew);

  // stage 2: AdaGN -> qkv -> attn -> proj -> + x1  => XR (=x2)
  k_statsT<<<256, 256, 0, stream>>>(XR, SG2);
  k_gemm_mfma<<<dim3(1024,3), 256, 0, stream>>>(
      XR, nullptr, nullptr, 128, qkvw, qkvb,
      nullptr, nullptr, nullptr, QKV, nullptr, 384, 0,
      SG2, gn2w, gn2b, SC + 2048, nullptr);
  k_attn<<<8192, 128, 0, stream>>>(QKV, relb, AO);
  k_gemm_mfma<<<dim3(1024,1), 256, 0, stream>>>(
      nullptr, nullptr, AO, 128, projw, projb,
      XR, nullptr, XR, nullptr, nullptr, 128, 0,
      nullptr, nullptr, nullptr, nullptr, nullptr);

  // stage 3: AdaGN -> mlp1(silu) -> mlp2 -> + x2  => XR (=x3)
  k_statsT<<<256, 256, 0, stream>>>(XR, SG3);
  k_gemm_mfma<<<dim3(1024,4), 256, 0, stream>>>(
      XR, nullptr, nullptr, 128, mlpw1, mlpb1,
      nullptr, nullptr, nullptr, H1, nullptr, 512, 1,
      SG3, gn3w, gn3b, SC + 4096, nullptr);
  k_gemm_mfma<<<dim3(1024,1), 256, 0, stream>>>(
      nullptr, nullptr, H1, 512, mlpw2, mlpb2,
      XR, nullptr, XR, nullptr, nullptr, 128, 0,
      nullptr, nullptr, nullptr, nullptr, nullptr);

  // stage 4: GN -> dw3x3 -> silu -> pw 1x1 -> + x3  => d_out [c][p] fp32
  k_statsT<<<256, 256, 0, stream>>>(XR, SG4);
  k_dw<<<16384, 256, 0, stream>>>(XR, SG4, sbgnw, sbgnb, dww, dwb, DWO);
  k_gemm_mfma<<<dim3(1024,1), 256, 0, stream>>>(
      nullptr, nullptr, DWO, 128, pww, pwb,
      XR, nullptr, nullptr, nullptr, out, 128, 0,
      nullptr, nullptr, nullptr, nullptr, nullptr);
}